// Round 5
// baseline (334.042 us; speedup 1.0000x reference)
//
#include <hip/hip_runtime.h>

#define N_NODES 50000
#define E_EDGES 800000
#define E2      (2 * E_EDGES)
#define D_DIM   200
#define C_CLS   10
#define NB_BUCKET 196                        // buckets of 256 rows (r>>8)
#define BATCH     4096                       // edges per scatter block
#define NB_SCATTER ((E2 + BATCH - 1) / BATCH)        // 391
#define NB_CONV    ((N_NODES * D_DIM / 4 + 255) / 256) // 9766
#define CAP       12288                      // stage slots/bucket
#define NWIN      13                         // column windows: c>>12 (1.6 MB of W0h each)
#define RPW       10                         // rows per wave in layer0 (50000 = 10*5000)
#define NB_L0     (N_NODES / RPW / 4)        // 1250 blocks = 5000 waves, ONE generation

static __device__ __forceinline__ unsigned f2bf(float f) {
    unsigned u = __float_as_uint(f);
    return (u + 0x7FFFu + ((u >> 16) & 1u)) >> 16;     // RNE, low 16 bits
}
static __device__ __forceinline__ float bf_lo(unsigned u) {
    return __uint_as_float(u << 16);
}
static __device__ __forceinline__ float bf_hi(unsigned u) {
    return __uint_as_float(u & 0xFFFF0000u);
}

// ---------------------------------------------------------------------------
// Fused convert + scatter. UNCHANGED (proven).
// ---------------------------------------------------------------------------
__global__ __launch_bounds__(256) void convert_scatter_kernel(
        const float* __restrict__ W0, unsigned short* __restrict__ W0h,
        const int* __restrict__ rows0, const int* __restrict__ cols0,
        const float* __restrict__ vals0,
        const int* __restrict__ rows1, const int* __restrict__ cols1,
        const float* __restrict__ vals1,
        int* __restrict__ bcur,
        int2* __restrict__ stage) {
    __shared__ int cntL[NB_BUCKET];
    __shared__ int baseL[NB_BUCKET];
    __shared__ int offL[NB_BUCKET];
    __shared__ int2 recL[BATCH];            // 32 KB

    if (blockIdx.x >= NB_SCATTER) {
        // ---- convert path (streaming, no LDS use) ----
        int i = ((blockIdx.x - NB_SCATTER) * 256 + threadIdx.x) * 4;
        if (i < N_NODES * D_DIM) {
            float4 f = *(const float4*)(W0 + i);
            uint2 p;
            p.x = f2bf(f.x) | (f2bf(f.y) << 16);
            p.y = f2bf(f.z) | (f2bf(f.w) << 16);
            *(uint2*)(W0h + i) = p;
        }
        return;
    }

    // ---- scatter path ----
    const int tid = threadIdx.x;
    const int e0 = blockIdx.x * BATCH;

    for (int b = tid; b < NB_BUCKET; b += 256) cntL[b] = 0;
    __syncthreads();

#pragma unroll
    for (int k = 0; k < BATCH / 256; ++k) {
        int idx = k * 256 + tid;
        int e = e0 + idx;
        if (e < E2) {
            int r, c;
            float v;
            if (e < E_EDGES) {
                r = rows0[e]; c = cols0[e]; v = vals0[e];
            } else {
                int e1 = e - E_EDGES;
                r = rows1[e1]; c = cols1[e1]; v = vals1[e1];
            }
            recL[idx] = make_int2((int)((unsigned)r | ((unsigned)c << 16)),
                                  __float_as_int(v));
            atomicAdd(&cntL[r >> 8], 1);
        }
    }
    __syncthreads();

    for (int b = tid; b < NB_BUCKET; b += 256) {
        int c = cntL[b];
        baseL[b] = (c > 0) ? atomicAdd(&bcur[b], c) : 0;
        offL[b] = 0;
    }
    __syncthreads();

#pragma unroll
    for (int k = 0; k < BATCH / 256; ++k) {
        int idx = k * 256 + tid;
        int e = e0 + idx;
        if (e < E2) {
            int2 rec = recL[idx];
            int b = (int)(((unsigned)rec.x & 0xFFFFu) >> 8);
            int pos = baseL[b] + atomicAdd(&offL[b], 1);
            stage[(size_t)b * CAP + pos] = rec;
        }
    }
}

// ---------------------------------------------------------------------------
// Build CSR, two-key counting sort (row, column-window). As round 4, plus:
// emits rowwin[row][0..13] = absolute cv4 offsets of each window segment
// boundary (rowwin[row][13] = row end). These are the cursors the kernel
// already computes in LDS — one extra 56B store per row.
// ---------------------------------------------------------------------------
__global__ __launch_bounds__(256) void build_csr_kernel(
        const int* __restrict__ bcur,
        const int2* __restrict__ stage,
        int* __restrict__ ticket,
        int2* __restrict__ rowseg,
        int* __restrict__ rowwin,
        unsigned* __restrict__ cv4) {
    __shared__ int hist[256 * NWIN];    // 13 KB: [row][window]
    __shared__ int ws4[4];
    __shared__ int sbase;
    const int b = blockIdx.x;
    const int tid = threadIdx.x;
    const int lane = tid & 63;
    const int w = tid >> 6;

    for (int i = tid; i < 256 * NWIN; i += 256) hist[i] = 0;
    __syncthreads();

    const int n = bcur[b];
    const int2* __restrict__ sp = stage + (size_t)b * CAP;
    for (int i = tid; i < n; i += 256) {
        unsigned u = (unsigned)sp[i].x;
        atomicAdd(&hist[(u & 255u) * NWIN + (u >> 28)], 1);   // u>>28 == c>>12, 0..12
    }
    __syncthreads();

    // Per-row total (thread tid owns row tid of this bucket).
    int rowtot = 0;
#pragma unroll
    for (int k = 0; k < NWIN; ++k) rowtot += hist[tid * NWIN + k];

    // Block inclusive scan of row totals.
    int v = rowtot;
#pragma unroll
    for (int off = 1; off < 64; off <<= 1) {
        int t = __shfl_up(v, off, 64);
        if (lane >= off) v += t;
    }
    if (lane == 63) ws4[w] = v;
    __syncthreads();
    if (tid == 0) {
        int s = 0;
#pragma unroll
        for (int k = 0; k < 4; ++k) { int t = ws4[k]; ws4[k] = s; s += t; }
    }
    __syncthreads();
    v += ws4[w];                              // inclusive over 256 rows

    if (tid == 255) sbase = atomicAdd(ticket, v);   // reserve [sbase, sbase+total)
    __syncthreads();

    const int start = sbase + v - rowtot;     // exclusive + base
    const int row = (b << 8) + tid;
    const bool live = (row < N_NODES);
    if (live) rowseg[row] = make_int2(start, rowtot);

    // Turn hist into global placement cursors; also persist them to rowwin.
    int* rw = rowwin + (size_t)row * 14;
    int c = start;
#pragma unroll
    for (int k = 0; k < NWIN; ++k) {
        int t = hist[tid * NWIN + k];
        hist[tid * NWIN + k] = c;
        if (live) rw[k] = c;
        c += t;
    }
    if (live) rw[NWIN] = c;                   // rw[13] = start + rowtot
    __syncthreads();

    for (int i = tid; i < n; i += 256) {
        int2 rec = sp[i];
        unsigned u = (unsigned)rec.x;
        int pos = atomicAdd(&hist[(u & 255u) * NWIN + (u >> 28)], 1);
        cv4[pos] = (u & 0xFFFF0000u) | f2bf(__int_as_float(rec.y));
    }
}

// ---------------------------------------------------------------------------
// Fused layer 0, v5: one-generation window sweep with precomputed ends.
//  - 5000 waves / 1250 blocks, all co-resident (launch_bounds(256,5) ->
//    >=5 blocks/CU capacity). Every wave starts window 0 at t=0 and
//    advances at data-uniform rate -> chip-wide window locality (round-1
//    measured FETCH 327->137 MB for exactly this touch order).
//  - Loop nest: w (runtime) / j (unrolled, STATIC a[j][*]) / segment
//    [cur[j], rowwin[row][w+1]). Trip counts are wave-uniform scalars
//    known before the loop: no tag checks (round-1 vmcnt drain), no
//    runtime accumulator indexing (round-2 scratch spill).
// ---------------------------------------------------------------------------
__global__ __launch_bounds__(256, 5) void spmm_layer0_fused_kernel(
        const int* __restrict__ rowwin,
        const unsigned* __restrict__ cv4,
        const unsigned short* __restrict__ W0h,
        const float* __restrict__ W1,
        const float* __restrict__ eps0,
        float* __restrict__ g) {
    __shared__ __align__(16) float W1Ts[C_CLS * D_DIM];   // [k][d] transposed
    for (int i = threadIdx.x; i < C_CLS * D_DIM; i += 256) {
        int k = i / D_DIM, d = i - k * D_DIM;
        W1Ts[i] = W1[d * C_CLS + k];
    }
    __syncthreads();

    const int lane = threadIdx.x & 63;
    const int wid = __builtin_amdgcn_readfirstlane(blockIdx.x * 4 + (threadIdx.x >> 6));
    const int n0 = wid * RPW;
    if (n0 >= N_NODES) return;                // whole-wave exit only
    const float s0 = 0.1f * (1.0f + eps0[0]);
    const bool act = (lane < 50);
    const uint2* __restrict__ F = (const uint2*)W0h;

    float a[RPW][4];
#pragma unroll
    for (int j = 0; j < RPW; ++j) { a[j][0] = a[j][1] = a[j][2] = a[j][3] = 0.f; }

    int cur[RPW];
#pragma unroll
    for (int j = 0; j < RPW; ++j) cur[j] = rowwin[(size_t)(n0 + j) * 14];

    for (int w = 0; w < NWIN; ++w) {
#pragma unroll
        for (int j = 0; j < RPW; ++j) {
            int e = cur[j];
            const int end = rowwin[(size_t)(n0 + j) * 14 + w + 1];
            for (; e + 2 <= end; e += 2) {
                unsigned w0 = cv4[e], w1 = cv4[e + 1];
                if (act) {
                    uint2 u0 = F[(size_t)(w0 >> 16) * 50 + lane];
                    uint2 u1 = F[(size_t)(w1 >> 16) * 50 + lane];
                    float v0 = __uint_as_float(w0 << 16);
                    float v1 = __uint_as_float(w1 << 16);
                    a[j][0] += v0 * bf_lo(u0.x) + v1 * bf_lo(u1.x);
                    a[j][1] += v0 * bf_hi(u0.x) + v1 * bf_hi(u1.x);
                    a[j][2] += v0 * bf_lo(u0.y) + v1 * bf_lo(u1.y);
                    a[j][3] += v0 * bf_hi(u0.y) + v1 * bf_hi(u1.y);
                }
            }
            if (e < end) {
                unsigned w0 = cv4[e];
                if (act) {
                    uint2 u0 = F[(size_t)(w0 >> 16) * 50 + lane];
                    float v0 = __uint_as_float(w0 << 16);
                    a[j][0] += v0 * bf_lo(u0.x);
                    a[j][1] += v0 * bf_hi(u0.x);
                    a[j][2] += v0 * bf_lo(u0.y);
                    a[j][3] += v0 * bf_hi(u0.y);
                }
                ++e;
            }
            cur[j] = e;
        }
    }

    // ---- epilogue: relu + @W1 (transposed, conflict-free float4 LDS reads) ----
    const float4* __restrict__ W1T4 = (const float4*)W1Ts;  // [C_CLS][50] float4
#pragma unroll
    for (int j = 0; j < RPW; ++j) {
        const int nn = n0 + j;
        float o[C_CLS];
#pragma unroll
        for (int k = 0; k < C_CLS; ++k) o[k] = 0.f;
        if (act) {
            uint2 wsv = F[(size_t)nn * 50 + lane];
            float b0 = fmaxf(a[j][0] + s0 * bf_lo(wsv.x), 0.f);
            float b1 = fmaxf(a[j][1] + s0 * bf_hi(wsv.x), 0.f);
            float b2 = fmaxf(a[j][2] + s0 * bf_lo(wsv.y), 0.f);
            float b3 = fmaxf(a[j][3] + s0 * bf_hi(wsv.y), 0.f);
#pragma unroll
            for (int k = 0; k < C_CLS; ++k) {
                float4 wv4 = W1T4[k * 50 + lane];   // ds_read_b128, conflict-free
                o[k] = b0 * wv4.x + b1 * wv4.y + b2 * wv4.z + b3 * wv4.w;
            }
        }
#pragma unroll
        for (int k = 0; k < C_CLS; ++k) {
            for (int off2 = 32; off2 > 0; off2 >>= 1)
                o[k] += __shfl_xor(o[k], off2, 64);
        }
        if (lane == 0) {
            float* gp = g + (size_t)nn * C_CLS;
#pragma unroll
            for (int k = 0; k < C_CLS; ++k) gp[k] = o[k];
        }
    }
}

// ---------------------------------------------------------------------------
// Light layer 1 (UNCHANGED; g is L2-resident, order-insensitive).
// ---------------------------------------------------------------------------
__global__ __launch_bounds__(256) void spmm_layer1_light_kernel(
        const int2* __restrict__ rowseg,
        const unsigned* __restrict__ cv4,
        const float* __restrict__ g,
        const float* __restrict__ eps1,
        float* __restrict__ out) {
    const int lane = threadIdx.x & 63;
    const int n = __builtin_amdgcn_readfirstlane(blockIdx.x * 4 + (threadIdx.x >> 6));
    if (n >= N_NODES) return;
    const int grp = lane / 10;          // 0..5 active, 6 for lanes 60-63 (idle)
    const int d   = lane - grp * 10;    // 0..9
    const float s1 = 0.1f * (1.0f + eps1[0]);

    const int2 seg = rowseg[n];
    const int beg  = seg.x;
    const int endp = seg.x + seg.y;
    float acc = 0.f;

    for (int base = beg; base < endp; base += 12) {
        if (grp < 6) {
            int ea = base + grp;
            int eb = base + 6 + grp;
            unsigned pa = (ea < endp) ? cv4[ea] : 0u;
            unsigned pb = (eb < endp) ? cv4[eb] : 0u;
            if (ea < endp)
                acc += __uint_as_float(pa << 16) * g[(size_t)(pa >> 16) * C_CLS + d];
            if (eb < endp)
                acc += __uint_as_float(pb << 16) * g[(size_t)(pb >> 16) * C_CLS + d];
        }
    }

    float t;
    t = __shfl(acc, lane + 10, 64); if (lane < 50) acc += t;
    t = __shfl(acc, lane + 20, 64); if (lane < 30) acc += t;
    t = __shfl(acc, lane + 40, 64); if (lane < 10) acc += t;

    if (lane < 10) {
        out[(size_t)n * C_CLS + d] = acc + s1 * g[(size_t)n * C_CLS + d];
    }
}

// ---------------------------------------------------------------------------
extern "C" void kernel_launch(void* const* d_in, const int* in_sizes, int n_in,
                              void* d_out, int out_size, void* d_ws, size_t ws_size,
                              hipStream_t stream) {
    // setup_inputs order: x, rows0, cols0, vals0, rows1, cols1, vals1, W0, W1, eps0, eps1
    const int*   rows0 = (const int*)d_in[1];
    const int*   cols0 = (const int*)d_in[2];
    const float* vals0 = (const float*)d_in[3];
    const int*   rows1 = (const int*)d_in[4];
    const int*   cols1 = (const int*)d_in[5];
    const float* vals1 = (const float*)d_in[6];
    const float* W0    = (const float*)d_in[7];
    const float* W1    = (const float*)d_in[8];
    const float* eps0  = (const float*)d_in[9];
    const float* eps1  = (const float*)d_in[10];
    float* out = (float*)d_out;

    char* ws = (char*)d_ws;
    size_t off = 0;
    auto alloc = [&](size_t bytes) {
        void* p = ws + off;
        off += (bytes + 255) & ~(size_t)255;
        return p;
    };
    unsigned short* W0h = (unsigned short*)alloc((size_t)N_NODES * D_DIM * 2);  // 20 MB
    float* g      = (float*)alloc((size_t)N_NODES * C_CLS * 4);                 // 2 MB
    int2* rowseg  = (int2*)alloc((size_t)N_NODES * 8);                          // 400 KB
    int* rowwin   = (int*)alloc((size_t)N_NODES * 14 * 4);                      // 2.8 MB
    int* bcur     = (int*)alloc((size_t)(NB_BUCKET + 1) * 4);                   // +ticket
    unsigned* cv4 = (unsigned*)alloc((size_t)E2 * 4);                           // 6.4 MB
    int2* stage   = (int2*)alloc((size_t)NB_BUCKET * CAP * 8);                  // 19.3 MB
    int* ticket   = bcur + NB_BUCKET;
    (void)ws_size;

    hipMemsetAsync(bcur, 0, (size_t)(NB_BUCKET + 1) * 4, stream);
    convert_scatter_kernel<<<NB_SCATTER + NB_CONV, 256, 0, stream>>>(
        W0, W0h, rows0, cols0, vals0, rows1, cols1, vals1, bcur, stage);
    build_csr_kernel<<<NB_BUCKET, 256, 0, stream>>>(
        bcur, stage, ticket, rowseg, rowwin, cv4);

    spmm_layer0_fused_kernel<<<NB_L0, 256, 0, stream>>>(
        rowwin, cv4, W0h, W1, eps0, g);
    const int spmm1_grid = (N_NODES + 3) / 4;
    spmm_layer1_light_kernel<<<spmm1_grid, 256, 0, stream>>>(
        rowseg, cv4, g, eps1, out);
}

// Round 6
// 279.880 us; speedup vs baseline: 1.1935x; 1.1935x over previous
//
#include <hip/hip_runtime.h>

#define N_NODES 50000
#define E_EDGES 800000
#define E2      (2 * E_EDGES)
#define D_DIM   200
#define C_CLS   10
#define NB_BUCKET 196                        // buckets of 256 rows (r>>8)
#define BATCH     4096                       // edges per scatter block
#define NB_SCATTER ((E2 + BATCH - 1) / BATCH)        // 391
#define NB_CONV    ((N_NODES * D_DIM / 4 + 255) / 256) // 9766
#define CAP       12288                      // stage slots/bucket
#define NWIN      13                         // column windows: c>>12 (1.6 MB of W0h each)
#define RPW       8                          // rows per wave in layer0 (sequential)
#define NB_L0     ((N_NODES / RPW + 3) / 4)  // 1563 blocks = 6250 waves ≈ one generation

static __device__ __forceinline__ unsigned f2bf(float f) {
    unsigned u = __float_as_uint(f);
    return (u + 0x7FFFu + ((u >> 16) & 1u)) >> 16;     // RNE, low 16 bits
}
static __device__ __forceinline__ float bf_lo(unsigned u) {
    return __uint_as_float(u << 16);
}
static __device__ __forceinline__ float bf_hi(unsigned u) {
    return __uint_as_float(u & 0xFFFF0000u);
}

// ---------------------------------------------------------------------------
// Fused convert + scatter. UNCHANGED (proven).
// ---------------------------------------------------------------------------
__global__ __launch_bounds__(256) void convert_scatter_kernel(
        const float* __restrict__ W0, unsigned short* __restrict__ W0h,
        const int* __restrict__ rows0, const int* __restrict__ cols0,
        const float* __restrict__ vals0,
        const int* __restrict__ rows1, const int* __restrict__ cols1,
        const float* __restrict__ vals1,
        int* __restrict__ bcur,
        int2* __restrict__ stage) {
    __shared__ int cntL[NB_BUCKET];
    __shared__ int baseL[NB_BUCKET];
    __shared__ int offL[NB_BUCKET];
    __shared__ int2 recL[BATCH];            // 32 KB

    if (blockIdx.x >= NB_SCATTER) {
        // ---- convert path (streaming, no LDS use) ----
        int i = ((blockIdx.x - NB_SCATTER) * 256 + threadIdx.x) * 4;
        if (i < N_NODES * D_DIM) {
            float4 f = *(const float4*)(W0 + i);
            uint2 p;
            p.x = f2bf(f.x) | (f2bf(f.y) << 16);
            p.y = f2bf(f.z) | (f2bf(f.w) << 16);
            *(uint2*)(W0h + i) = p;
        }
        return;
    }

    // ---- scatter path ----
    const int tid = threadIdx.x;
    const int e0 = blockIdx.x * BATCH;

    for (int b = tid; b < NB_BUCKET; b += 256) cntL[b] = 0;
    __syncthreads();

#pragma unroll
    for (int k = 0; k < BATCH / 256; ++k) {
        int idx = k * 256 + tid;
        int e = e0 + idx;
        if (e < E2) {
            int r, c;
            float v;
            if (e < E_EDGES) {
                r = rows0[e]; c = cols0[e]; v = vals0[e];
            } else {
                int e1 = e - E_EDGES;
                r = rows1[e1]; c = cols1[e1]; v = vals1[e1];
            }
            recL[idx] = make_int2((int)((unsigned)r | ((unsigned)c << 16)),
                                  __float_as_int(v));
            atomicAdd(&cntL[r >> 8], 1);
        }
    }
    __syncthreads();

    for (int b = tid; b < NB_BUCKET; b += 256) {
        int c = cntL[b];
        baseL[b] = (c > 0) ? atomicAdd(&bcur[b], c) : 0;
        offL[b] = 0;
    }
    __syncthreads();

#pragma unroll
    for (int k = 0; k < BATCH / 256; ++k) {
        int idx = k * 256 + tid;
        int e = e0 + idx;
        if (e < E2) {
            int2 rec = recL[idx];
            int b = (int)(((unsigned)rec.x & 0xFFFFu) >> 8);
            int pos = baseL[b] + atomicAdd(&offL[b], 1);
            stage[(size_t)b * CAP + pos] = rec;
        }
    }
}

// ---------------------------------------------------------------------------
// Build CSR, two-key counting sort (row, column-window). Round-4 version
// verbatim: window-sorted per-row cv4 segments, rowseg = (start, count).
// ---------------------------------------------------------------------------
__global__ __launch_bounds__(256) void build_csr_kernel(
        const int* __restrict__ bcur,
        const int2* __restrict__ stage,
        int* __restrict__ ticket,
        int2* __restrict__ rowseg,
        unsigned* __restrict__ cv4) {
    __shared__ int hist[256 * NWIN];    // 13 KB: [row][window]
    __shared__ int ws4[4];
    __shared__ int sbase;
    const int b = blockIdx.x;
    const int tid = threadIdx.x;
    const int lane = tid & 63;
    const int w = tid >> 6;

    for (int i = tid; i < 256 * NWIN; i += 256) hist[i] = 0;
    __syncthreads();

    const int n = bcur[b];
    const int2* __restrict__ sp = stage + (size_t)b * CAP;
    for (int i = tid; i < n; i += 256) {
        unsigned u = (unsigned)sp[i].x;
        atomicAdd(&hist[(u & 255u) * NWIN + (u >> 28)], 1);   // u>>28 == c>>12, 0..12
    }
    __syncthreads();

    // Per-row total (thread tid owns row tid of this bucket).
    int rowtot = 0;
#pragma unroll
    for (int k = 0; k < NWIN; ++k) rowtot += hist[tid * NWIN + k];

    // Block inclusive scan of row totals.
    int v = rowtot;
#pragma unroll
    for (int off = 1; off < 64; off <<= 1) {
        int t = __shfl_up(v, off, 64);
        if (lane >= off) v += t;
    }
    if (lane == 63) ws4[w] = v;
    __syncthreads();
    if (tid == 0) {
        int s = 0;
#pragma unroll
        for (int k = 0; k < 4; ++k) { int t = ws4[k]; ws4[k] = s; s += t; }
    }
    __syncthreads();
    v += ws4[w];                              // inclusive over 256 rows

    if (tid == 255) sbase = atomicAdd(ticket, v);   // reserve [sbase, sbase+total)
    __syncthreads();

    const int start = sbase + v - rowtot;     // exclusive + base
    const int row = (b << 8) + tid;
    if (row < N_NODES) rowseg[row] = make_int2(start, rowtot);

    // Turn hist into global placement cursors (exclusive scan within row).
    int c = start;
#pragma unroll
    for (int k = 0; k < NWIN; ++k) {
        int t = hist[tid * NWIN + k];
        hist[tid * NWIN + k] = c;
        c += t;
    }
    __syncthreads();

    for (int i = tid; i < n; i += 256) {
        int2 rec = sp[i];
        unsigned u = (unsigned)rec.x;
        int pos = atomicAdd(&hist[(u & 255u) * NWIN + (u >> 28)], 1);
        cv4[pos] = (u & 0xFFFF0000u) | f2bf(__int_as_float(rec.y));
    }
}

// ---------------------------------------------------------------------------
// Fused layer 0, v6: one-generation + sequential rows + deep ILP.
//  - 6250 waves (1563 blocks, launch_bounds(256,6)): ~all co-resident, one
//    generation. Each wave owns 8 consecutive rows, processed SEQUENTIALLY
//    with a LINEAR unroll-16 walk (no per-segment bounds -> no vmcnt drain,
//    no runtime-indexed accumulators -> no scratch; a0..a3 scalars reused).
//  - Window-sorted rows + aligned generation => all waves touch window
//    ~13k/32 at edge k: chip-wide live set ~3-4 windows (~5 MB), partial
//    L2 fit (v5 proved full alignment -> 143 MB FETCH; this trades some
//    alignment for v4's proven gather pipeline, now 16 deep).
//  - Accumulate statements grouped 8 terms exactly as round-4 => the
//    fp32 add sequence per accumulator is bit-identical to the passing run.
// ---------------------------------------------------------------------------
__global__ __launch_bounds__(256, 6) void spmm_layer0_fused_kernel(
        const int2* __restrict__ rowseg,
        const unsigned* __restrict__ cv4,
        const unsigned short* __restrict__ W0h,
        const float* __restrict__ W1,
        const float* __restrict__ eps0,
        float* __restrict__ g) {
    __shared__ __align__(16) float W1Ts[C_CLS * D_DIM];   // [k][d] transposed
    for (int i = threadIdx.x; i < C_CLS * D_DIM; i += 256) {
        int k = i / D_DIM, d = i - k * D_DIM;
        W1Ts[i] = W1[d * C_CLS + k];
    }
    __syncthreads();

    const int lane = threadIdx.x & 63;
    const int wid = __builtin_amdgcn_readfirstlane(blockIdx.x * 4 + (threadIdx.x >> 6));
    const int n0 = wid * RPW;
    if (n0 >= N_NODES) return;                // whole-wave exit only (50000%8==0)
    const float s0 = 0.1f * (1.0f + eps0[0]);
    const bool act = (lane < 50);
    const uint2* __restrict__ F = (const uint2*)W0h;
    const float4* __restrict__ W1T4 = (const float4*)W1Ts;  // [C_CLS][50] float4

    for (int j = 0; j < RPW; ++j) {
        const int n = n0 + j;
        const int2 seg = rowseg[n];
        const int beg  = seg.x;
        const int endp = seg.x + seg.y;
        float a0 = 0.f, a1 = 0.f, a2 = 0.f, a3 = 0.f;

        int e = beg;
        for (; e + 16 <= endp; e += 16) {
            unsigned w0  = cv4[e],      w1  = cv4[e + 1],  w2  = cv4[e + 2],  w3  = cv4[e + 3];
            unsigned w4  = cv4[e + 4],  w5  = cv4[e + 5],  w6  = cv4[e + 6],  w7  = cv4[e + 7];
            unsigned w8  = cv4[e + 8],  w9  = cv4[e + 9],  w10 = cv4[e + 10], w11 = cv4[e + 11];
            unsigned w12 = cv4[e + 12], w13 = cv4[e + 13], w14 = cv4[e + 14], w15 = cv4[e + 15];
            if (act) {
                uint2 u0  = F[(size_t)(w0  >> 16) * 50 + lane];
                uint2 u1  = F[(size_t)(w1  >> 16) * 50 + lane];
                uint2 u2  = F[(size_t)(w2  >> 16) * 50 + lane];
                uint2 u3  = F[(size_t)(w3  >> 16) * 50 + lane];
                uint2 u4  = F[(size_t)(w4  >> 16) * 50 + lane];
                uint2 u5  = F[(size_t)(w5  >> 16) * 50 + lane];
                uint2 u6  = F[(size_t)(w6  >> 16) * 50 + lane];
                uint2 u7  = F[(size_t)(w7  >> 16) * 50 + lane];
                uint2 u8  = F[(size_t)(w8  >> 16) * 50 + lane];
                uint2 u9  = F[(size_t)(w9  >> 16) * 50 + lane];
                uint2 u10 = F[(size_t)(w10 >> 16) * 50 + lane];
                uint2 u11 = F[(size_t)(w11 >> 16) * 50 + lane];
                uint2 u12 = F[(size_t)(w12 >> 16) * 50 + lane];
                uint2 u13 = F[(size_t)(w13 >> 16) * 50 + lane];
                uint2 u14 = F[(size_t)(w14 >> 16) * 50 + lane];
                uint2 u15 = F[(size_t)(w15 >> 16) * 50 + lane];
                float v0  = __uint_as_float(w0  << 16), v1  = __uint_as_float(w1  << 16);
                float v2  = __uint_as_float(w2  << 16), v3  = __uint_as_float(w3  << 16);
                float v4  = __uint_as_float(w4  << 16), v5  = __uint_as_float(w5  << 16);
                float v6  = __uint_as_float(w6  << 16), v7  = __uint_as_float(w7  << 16);
                float v8  = __uint_as_float(w8  << 16), v9  = __uint_as_float(w9  << 16);
                float v10 = __uint_as_float(w10 << 16), v11 = __uint_as_float(w11 << 16);
                float v12 = __uint_as_float(w12 << 16), v13 = __uint_as_float(w13 << 16);
                float v14 = __uint_as_float(w14 << 16), v15 = __uint_as_float(w15 << 16);
                a0 += v0 * bf_lo(u0.x) + v1 * bf_lo(u1.x) + v2 * bf_lo(u2.x) + v3 * bf_lo(u3.x)
                    + v4 * bf_lo(u4.x) + v5 * bf_lo(u5.x) + v6 * bf_lo(u6.x) + v7 * bf_lo(u7.x);
                a0 += v8 * bf_lo(u8.x) + v9 * bf_lo(u9.x) + v10 * bf_lo(u10.x) + v11 * bf_lo(u11.x)
                    + v12 * bf_lo(u12.x) + v13 * bf_lo(u13.x) + v14 * bf_lo(u14.x) + v15 * bf_lo(u15.x);
                a1 += v0 * bf_hi(u0.x) + v1 * bf_hi(u1.x) + v2 * bf_hi(u2.x) + v3 * bf_hi(u3.x)
                    + v4 * bf_hi(u4.x) + v5 * bf_hi(u5.x) + v6 * bf_hi(u6.x) + v7 * bf_hi(u7.x);
                a1 += v8 * bf_hi(u8.x) + v9 * bf_hi(u9.x) + v10 * bf_hi(u10.x) + v11 * bf_hi(u11.x)
                    + v12 * bf_hi(u12.x) + v13 * bf_hi(u13.x) + v14 * bf_hi(u14.x) + v15 * bf_hi(u15.x);
                a2 += v0 * bf_lo(u0.y) + v1 * bf_lo(u1.y) + v2 * bf_lo(u2.y) + v3 * bf_lo(u3.y)
                    + v4 * bf_lo(u4.y) + v5 * bf_lo(u5.y) + v6 * bf_lo(u6.y) + v7 * bf_lo(u7.y);
                a2 += v8 * bf_lo(u8.y) + v9 * bf_lo(u9.y) + v10 * bf_lo(u10.y) + v11 * bf_lo(u11.y)
                    + v12 * bf_lo(u12.y) + v13 * bf_lo(u13.y) + v14 * bf_lo(u14.y) + v15 * bf_lo(u15.y);
                a3 += v0 * bf_hi(u0.y) + v1 * bf_hi(u1.y) + v2 * bf_hi(u2.y) + v3 * bf_hi(u3.y)
                    + v4 * bf_hi(u4.y) + v5 * bf_hi(u5.y) + v6 * bf_hi(u6.y) + v7 * bf_hi(u7.y);
                a3 += v8 * bf_hi(u8.y) + v9 * bf_hi(u9.y) + v10 * bf_hi(u10.y) + v11 * bf_hi(u11.y)
                    + v12 * bf_hi(u12.y) + v13 * bf_hi(u13.y) + v14 * bf_hi(u14.y) + v15 * bf_hi(u15.y);
            }
        }
        for (; e + 8 <= endp; e += 8) {
            unsigned w0 = cv4[e],     w1 = cv4[e + 1], w2 = cv4[e + 2], w3 = cv4[e + 3];
            unsigned w4 = cv4[e + 4], w5 = cv4[e + 5], w6 = cv4[e + 6], w7 = cv4[e + 7];
            if (act) {
                uint2 u0 = F[(size_t)(w0 >> 16) * 50 + lane];
                uint2 u1 = F[(size_t)(w1 >> 16) * 50 + lane];
                uint2 u2 = F[(size_t)(w2 >> 16) * 50 + lane];
                uint2 u3 = F[(size_t)(w3 >> 16) * 50 + lane];
                uint2 u4 = F[(size_t)(w4 >> 16) * 50 + lane];
                uint2 u5 = F[(size_t)(w5 >> 16) * 50 + lane];
                uint2 u6 = F[(size_t)(w6 >> 16) * 50 + lane];
                uint2 u7 = F[(size_t)(w7 >> 16) * 50 + lane];
                float v0 = __uint_as_float(w0 << 16), v1 = __uint_as_float(w1 << 16);
                float v2 = __uint_as_float(w2 << 16), v3 = __uint_as_float(w3 << 16);
                float v4 = __uint_as_float(w4 << 16), v5 = __uint_as_float(w5 << 16);
                float v6 = __uint_as_float(w6 << 16), v7 = __uint_as_float(w7 << 16);
                a0 += v0 * bf_lo(u0.x) + v1 * bf_lo(u1.x) + v2 * bf_lo(u2.x) + v3 * bf_lo(u3.x)
                    + v4 * bf_lo(u4.x) + v5 * bf_lo(u5.x) + v6 * bf_lo(u6.x) + v7 * bf_lo(u7.x);
                a1 += v0 * bf_hi(u0.x) + v1 * bf_hi(u1.x) + v2 * bf_hi(u2.x) + v3 * bf_hi(u3.x)
                    + v4 * bf_hi(u4.x) + v5 * bf_hi(u5.x) + v6 * bf_hi(u6.x) + v7 * bf_hi(u7.x);
                a2 += v0 * bf_lo(u0.y) + v1 * bf_lo(u1.y) + v2 * bf_lo(u2.y) + v3 * bf_lo(u3.y)
                    + v4 * bf_lo(u4.y) + v5 * bf_lo(u5.y) + v6 * bf_lo(u6.y) + v7 * bf_lo(u7.y);
                a3 += v0 * bf_hi(u0.y) + v1 * bf_hi(u1.y) + v2 * bf_hi(u2.y) + v3 * bf_hi(u3.y)
                    + v4 * bf_hi(u4.y) + v5 * bf_hi(u5.y) + v6 * bf_hi(u6.y) + v7 * bf_hi(u7.y);
            }
        }
        for (; e + 4 <= endp; e += 4) {
            unsigned w0 = cv4[e], w1 = cv4[e + 1], w2 = cv4[e + 2], w3 = cv4[e + 3];
            if (act) {
                uint2 u0 = F[(size_t)(w0 >> 16) * 50 + lane];
                uint2 u1 = F[(size_t)(w1 >> 16) * 50 + lane];
                uint2 u2 = F[(size_t)(w2 >> 16) * 50 + lane];
                uint2 u3 = F[(size_t)(w3 >> 16) * 50 + lane];
                float v0 = __uint_as_float(w0 << 16), v1 = __uint_as_float(w1 << 16);
                float v2 = __uint_as_float(w2 << 16), v3 = __uint_as_float(w3 << 16);
                a0 += v0 * bf_lo(u0.x) + v1 * bf_lo(u1.x) + v2 * bf_lo(u2.x) + v3 * bf_lo(u3.x);
                a1 += v0 * bf_hi(u0.x) + v1 * bf_hi(u1.x) + v2 * bf_hi(u2.x) + v3 * bf_hi(u3.x);
                a2 += v0 * bf_lo(u0.y) + v1 * bf_lo(u1.y) + v2 * bf_lo(u2.y) + v3 * bf_lo(u3.y);
                a3 += v0 * bf_hi(u0.y) + v1 * bf_hi(u1.y) + v2 * bf_hi(u2.y) + v3 * bf_hi(u3.y);
            }
        }
        for (; e < endp; ++e) {
            unsigned w = cv4[e];
            if (act) {
                uint2 u = F[(size_t)(w >> 16) * 50 + lane];
                float v = __uint_as_float(w << 16);
                a0 += v * bf_lo(u.x);
                a1 += v * bf_hi(u.x);
                a2 += v * bf_lo(u.y);
                a3 += v * bf_hi(u.y);
            }
        }

        // ---- per-row epilogue: relu + @W1 (transposed, conflict-free) ----
        float o[C_CLS];
#pragma unroll
        for (int k = 0; k < C_CLS; ++k) o[k] = 0.f;
        if (act) {
            uint2 wsv = F[(size_t)n * 50 + lane];
            float b0 = fmaxf(a0 + s0 * bf_lo(wsv.x), 0.f);
            float b1 = fmaxf(a1 + s0 * bf_hi(wsv.x), 0.f);
            float b2 = fmaxf(a2 + s0 * bf_lo(wsv.y), 0.f);
            float b3 = fmaxf(a3 + s0 * bf_hi(wsv.y), 0.f);
#pragma unroll
            for (int k = 0; k < C_CLS; ++k) {
                float4 wv = W1T4[k * 50 + lane];   // ds_read_b128, conflict-free
                o[k] = b0 * wv.x + b1 * wv.y + b2 * wv.z + b3 * wv.w;
            }
        }
#pragma unroll
        for (int k = 0; k < C_CLS; ++k) {
            for (int off = 32; off > 0; off >>= 1)
                o[k] += __shfl_xor(o[k], off, 64);
        }
        if (lane == 0) {
            float* gp = g + (size_t)n * C_CLS;
#pragma unroll
            for (int k = 0; k < C_CLS; ++k) gp[k] = o[k];
        }
    }
}

// ---------------------------------------------------------------------------
// Light layer 1 (UNCHANGED).
// ---------------------------------------------------------------------------
__global__ __launch_bounds__(256) void spmm_layer1_light_kernel(
        const int2* __restrict__ rowseg,
        const unsigned* __restrict__ cv4,
        const float* __restrict__ g,
        const float* __restrict__ eps1,
        float* __restrict__ out) {
    const int lane = threadIdx.x & 63;
    const int n = __builtin_amdgcn_readfirstlane(blockIdx.x * 4 + (threadIdx.x >> 6));
    if (n >= N_NODES) return;
    const int grp = lane / 10;          // 0..5 active, 6 for lanes 60-63 (idle)
    const int d   = lane - grp * 10;    // 0..9
    const float s1 = 0.1f * (1.0f + eps1[0]);

    const int2 seg = rowseg[n];
    const int beg  = seg.x;
    const int endp = seg.x + seg.y;
    float acc = 0.f;

    for (int base = beg; base < endp; base += 12) {
        if (grp < 6) {
            int ea = base + grp;
            int eb = base + 6 + grp;
            unsigned pa = (ea < endp) ? cv4[ea] : 0u;
            unsigned pb = (eb < endp) ? cv4[eb] : 0u;
            if (ea < endp)
                acc += __uint_as_float(pa << 16) * g[(size_t)(pa >> 16) * C_CLS + d];
            if (eb < endp)
                acc += __uint_as_float(pb << 16) * g[(size_t)(pb >> 16) * C_CLS + d];
        }
    }

    float t;
    t = __shfl(acc, lane + 10, 64); if (lane < 50) acc += t;
    t = __shfl(acc, lane + 20, 64); if (lane < 30) acc += t;
    t = __shfl(acc, lane + 40, 64); if (lane < 10) acc += t;

    if (lane < 10) {
        out[(size_t)n * C_CLS + d] = acc + s1 * g[(size_t)n * C_CLS + d];
    }
}

// ---------------------------------------------------------------------------
extern "C" void kernel_launch(void* const* d_in, const int* in_sizes, int n_in,
                              void* d_out, int out_size, void* d_ws, size_t ws_size,
                              hipStream_t stream) {
    // setup_inputs order: x, rows0, cols0, vals0, rows1, cols1, vals1, W0, W1, eps0, eps1
    const int*   rows0 = (const int*)d_in[1];
    const int*   cols0 = (const int*)d_in[2];
    const float* vals0 = (const float*)d_in[3];
    const int*   rows1 = (const int*)d_in[4];
    const int*   cols1 = (const int*)d_in[5];
    const float* vals1 = (const float*)d_in[6];
    const float* W0    = (const float*)d_in[7];
    const float* W1    = (const float*)d_in[8];
    const float* eps0  = (const float*)d_in[9];
    const float* eps1  = (const float*)d_in[10];
    float* out = (float*)d_out;

    char* ws = (char*)d_ws;
    size_t off = 0;
    auto alloc = [&](size_t bytes) {
        void* p = ws + off;
        off += (bytes + 255) & ~(size_t)255;
        return p;
    };
    unsigned short* W0h = (unsigned short*)alloc((size_t)N_NODES * D_DIM * 2);  // 20 MB
    float* g      = (float*)alloc((size_t)N_NODES * C_CLS * 4);                 // 2 MB
    int2* rowseg  = (int2*)alloc((size_t)N_NODES * 8);                          // 400 KB
    int* bcur     = (int*)alloc((size_t)(NB_BUCKET + 1) * 4);                   // +ticket
    unsigned* cv4 = (unsigned*)alloc((size_t)E2 * 4);                           // 6.4 MB
    int2* stage   = (int2*)alloc((size_t)NB_BUCKET * CAP * 8);                  // 19.3 MB
    int* ticket   = bcur + NB_BUCKET;
    (void)ws_size;

    hipMemsetAsync(bcur, 0, (size_t)(NB_BUCKET + 1) * 4, stream);
    convert_scatter_kernel<<<NB_SCATTER + NB_CONV, 256, 0, stream>>>(
        W0, W0h, rows0, cols0, vals0, rows1, cols1, vals1, bcur, stage);
    build_csr_kernel<<<NB_BUCKET, 256, 0, stream>>>(bcur, stage, ticket, rowseg, cv4);

    spmm_layer0_fused_kernel<<<NB_L0, 256, 0, stream>>>(
        rowseg, cv4, W0h, W1, eps0, g);
    const int spmm1_grid = (N_NODES + 3) / 4;
    spmm_layer1_light_kernel<<<spmm1_grid, 256, 0, stream>>>(
        rowseg, cv4, g, eps1, out);
}